// Round 2
// baseline (10410.996 us; speedup 1.0000x reference)
//
#include <hip/hip_runtime.h>
#include <math.h>

// ---------------- problem constants ----------------
constexpr int Zd   = 256;          // lambda/p dim
constexpr int Tt   = 16;           // frames
constexpr int NF   = 512;          // MLP hidden
constexpr int Hh   = 512;          // LSTM hidden
constexpr int NL   = 9;            // coupling layers
constexpr int Bb   = 1024;         // batch
constexpr int BT   = Bb * Tt;      // 16384 flattened rows
constexpr float LOG_SQRT_2PI_F = 0.9189385332046727f;

// ---------------- GEMM tiling ----------------
constexpr int BM = 64;
constexpr int BN = 64;
constexpr int BK = 16;

// mask[i][k] == 1 ?  layer 0 = zeros; odd layer ('a') = odd k; even layer>0 ('b') = even k
__device__ __forceinline__ bool maskbit(int layer, int k) {
  if (layer == 0) return false;
  return (layer & 1) ? ((k & 1) != 0) : ((k & 1) == 0);
}

enum { AM_DIRECT = 0, AM_FLOW = 1 };
enum { EP_LEAKY = 0, EP_TANH_MASK = 1, EP_MASK = 2, EP_BIAS2 = 3, EP_ACC = 4, EP_BIAS = 5 };

// C[M,N] = epilogue( A[M,K] @ W[N,K]^T ), fp32, LDS tiled.
// AM_FLOW synthesizes A on the fly: k<Z -> (layer==0 ? z_shift : mask*z), k>=Z -> p.
// A==nullptr (AM_DIRECT) means A is all zeros (LSTM t=0 input).
template <int AMODE, int EPI>
__global__ __launch_bounds__(256)
void gemm_k(const float* __restrict__ A, int lda,
            const float* __restrict__ W,
            const float* __restrict__ bias,
            const float* __restrict__ bias2,
            float* __restrict__ C,
            int N, int K,
            const float* __restrict__ zbuf,
            const float* __restrict__ pbuf,
            int layer)
{
  __shared__ float As[BK][BM];
  __shared__ float Ws[BK][BN];
  const int bm  = blockIdx.x * BM;
  const int bn  = blockIdx.y * BN;
  const int tid = threadIdx.x;
  const int tx  = tid & 15;        // 16 thread cols
  const int ty  = tid >> 4;        // 16 thread rows
  const int lr  = tid >> 2;        // load row 0..63
  const int lk  = (tid & 3) << 2;  // load k offset 0,4,8,12

  float acc[4][4] = {};

  for (int k0 = 0; k0 < K; k0 += BK) {
    float av[4];
    if (AMODE == AM_FLOW) {
      const int m = bm + lr;
#pragma unroll
      for (int j = 0; j < 4; ++j) {
        const int k = k0 + lk + j;
        float v;
        if (k < Zd) {
          if (layer == 0) {
            v = ((m & (Tt - 1)) == 0) ? 0.f : zbuf[(size_t)(m - 1) * Zd + k];
          } else {
            v = maskbit(layer, k) ? zbuf[(size_t)m * Zd + k] : 0.f;
          }
        } else {
          v = pbuf[(size_t)m * Zd + (k - Zd)];
        }
        av[j] = v;
      }
    } else {
      if (A) {
        const float4 v = *(const float4*)(A + (size_t)(bm + lr) * lda + k0 + lk);
        av[0] = v.x; av[1] = v.y; av[2] = v.z; av[3] = v.w;
      } else {
        av[0] = av[1] = av[2] = av[3] = 0.f;
      }
    }
    As[lk + 0][lr] = av[0];
    As[lk + 1][lr] = av[1];
    As[lk + 2][lr] = av[2];
    As[lk + 3][lr] = av[3];

    const float4 wv = *(const float4*)(W + (size_t)(bn + lr) * K + k0 + lk);
    Ws[lk + 0][lr] = wv.x;
    Ws[lk + 1][lr] = wv.y;
    Ws[lk + 2][lr] = wv.z;
    Ws[lk + 3][lr] = wv.w;

    __syncthreads();
#pragma unroll
    for (int kk = 0; kk < BK; ++kk) {
      const float4 a = *(const float4*)&As[kk][ty << 2];
      const float4 b = *(const float4*)&Ws[kk][tx << 2];
      const float aa[4] = {a.x, a.y, a.z, a.w};
      const float bb[4] = {b.x, b.y, b.z, b.w};
#pragma unroll
      for (int i = 0; i < 4; ++i)
#pragma unroll
        for (int j = 0; j < 4; ++j)
          acc[i][j] = fmaf(aa[i], bb[j], acc[i][j]);
    }
    __syncthreads();
  }

#pragma unroll
  for (int i = 0; i < 4; ++i) {
    const int m = bm + (ty << 2) + i;
#pragma unroll
    for (int j = 0; j < 4; ++j) {
      const int n = bn + (tx << 2) + j;
      float v = acc[i][j];
      float* cp = C + (size_t)m * N + n;
      if (EPI == EP_LEAKY) {
        v += bias[n];
        v = v > 0.f ? v : 0.01f * v;
        *cp = v;
      } else if (EPI == EP_TANH_MASK) {
        v += bias[n];
        v = tanhf(v);
        *cp = maskbit(layer, n) ? 0.f : v;
      } else if (EPI == EP_MASK) {
        v += bias[n];
        *cp = maskbit(layer, n) ? 0.f : v;
      } else if (EPI == EP_BIAS2) {
        *cp = v + bias[n] + bias2[n];
      } else if (EPI == EP_ACC) {
        *cp += v;
      } else { // EP_BIAS
        *cp = v + bias[n];
      }
    }
  }
}

// ---------------- elementwise / reduction kernels ----------------

__device__ __forceinline__ double block_reduce_d(double v) {
  __shared__ double sred[4];
#pragma unroll
  for (int off = 32; off > 0; off >>= 1) v += __shfl_down(v, off);
  const int lane = threadIdx.x & 63;
  const int w    = threadIdx.x >> 6;
  if (lane == 0) sred[w] = v;
  __syncthreads();
  double r = 0.0;
  if (threadIdx.x == 0) {
    const int nw = blockDim.x >> 6;
    r = sred[0];
    for (int i = 1; i < nw; ++i) r += sred[i];
  }
  return r;
}

__global__ __launch_bounds__(256)
void split_k(const float* __restrict__ nf, float* __restrict__ z, float* __restrict__ p) {
  const int n = BT * Zd / 4;
  for (int i = blockIdx.x * blockDim.x + threadIdx.x; i < n; i += gridDim.x * blockDim.x) {
    const int m  = i / (Zd / 4);
    const int kq = i - m * (Zd / 4);
    const float4* row = (const float4*)nf + (size_t)m * (2 * Zd / 4);
    ((float4*)p)[i] = row[kq];
    ((float4*)z)[i] = row[(Zd / 4) + kq];
  }
}

// z <- mask ? z : (z - t)*exp(-s);  ldj[m] -= sum_k s[m,k]
__global__ __launch_bounds__(256)
void flow_update_k(float* __restrict__ z, const float* __restrict__ s,
                   const float* __restrict__ t, float* __restrict__ ldj, int layer) {
  const int m = blockIdx.x;
  const int k = threadIdx.x;
  const size_t idx = (size_t)m * Zd + k;
  const float sv = s[idx];
  const float tv = t[idx];
  const float zv = z[idx];
  z[idx] = maskbit(layer, k) ? zv : (zv - tv) * expf(-sv);

  __shared__ float red[256];
  red[k] = sv;
  __syncthreads();
  for (int off = 128; off > 0; off >>= 1) {
    if (k < off) red[k] += red[k + off];
    __syncthreads();
  }
  if (k == 0) ldj[m] -= red[0];
}

// write z3 to out[1..] and accumulate sum(logN(z3)) into acc[1]
__global__ __launch_bounds__(256)
void z3_out_k(const float* __restrict__ z, float* __restrict__ out, double* __restrict__ acc) {
  const int n = BT * Zd;
  double local = 0.0;
  for (int i = blockIdx.x * blockDim.x + threadIdx.x; i < n; i += gridDim.x * blockDim.x) {
    const float v = z[i];
    out[1 + i] = v;
    local += (double)(-0.5f * v * v - LOG_SQRT_2PI_F);
  }
  local = block_reduce_d(local);
  if (threadIdx.x == 0) atomicAdd(acc + 1, local);
}

__global__ __launch_bounds__(256)
void ldj_sum_k(const float* __restrict__ ldj, double* __restrict__ acc) {
  double local = 0.0;
  for (int i = blockIdx.x * blockDim.x + threadIdx.x; i < BT; i += gridDim.x * blockDim.x)
    local += (double)ldj[i];
  local = block_reduce_d(local);
  if (threadIdx.x == 0) atomicAdd(acc + 1, local);
}

// torch LSTMCell: gates [B, 4H] in i,f,g,o order; h,c updated in place
__global__ __launch_bounds__(256)
void lstm_cell_k(const float* __restrict__ g, float* __restrict__ h, float* __restrict__ c) {
  const int idx = blockIdx.x * blockDim.x + threadIdx.x; // < Bb*Hh
  const int m = idx >> 9;   // /512
  const int j = idx & 511;
  const float* gm = g + (size_t)m * (4 * Hh);
  const float gi = gm[j];
  const float gf = gm[Hh + j];
  const float gg = gm[2 * Hh + j];
  const float go = gm[3 * Hh + j];
  const float si = 1.f / (1.f + expf(-gi));
  const float sf = 1.f / (1.f + expf(-gf));
  const float so = 1.f / (1.f + expf(-go));
  const float c2 = sf * c[idx] + si * tanhf(gg);
  h[idx] = so * tanhf(c2);
  c[idx] = c2;
}

// accumulate sum(logN((z3_t - mean)*exp(-lv))) + sum(-lv) into acc[0]
__global__ __launch_bounds__(256)
void post_k(const float* __restrict__ mean, const float* __restrict__ lv,
            const float* __restrict__ z, int t, double* __restrict__ acc) {
  const int b = blockIdx.x;
  const int k = threadIdx.x;
  const float lvv = lv[(size_t)b * Zd + k];
  const float mv  = mean[(size_t)b * Zd + k];
  const float zv  = z[((size_t)b * Tt + t) * Zd + k];
  const float d   = (zv - mv) * expf(-lvv);
  double local = (double)(-0.5f * d * d - LOG_SQRT_2PI_F) - (double)lvv;
  local = block_reduce_d(local);
  if (threadIdx.x == 0) atomicAdd(acc + 0, local);
}

__global__ void finalize_k(const double* __restrict__ acc, float* __restrict__ out) {
  const double loglik = 0.0025 * acc[0] + acc[1];
  out[0] = (float)(-loglik / (double)Bb);
}

// ---------------- host launch ----------------
extern "C" void kernel_launch(void* const* d_in, const int* in_sizes, int n_in,
                              void* d_out, int out_size, void* d_ws, size_t ws_size,
                              hipStream_t stream) {
  (void)in_sizes; (void)n_in; (void)out_size; (void)ws_size;

  const float* nf    = (const float*)d_in[0];
  const float* sW1   = (const float*)d_in[1];
  const float* sb1   = (const float*)d_in[2];
  const float* sW2   = (const float*)d_in[3];
  const float* sb2   = (const float*)d_in[4];
  const float* sW3   = (const float*)d_in[5];
  const float* sb3   = (const float*)d_in[6];
  const float* tW1   = (const float*)d_in[7];
  const float* tb1   = (const float*)d_in[8];
  const float* tW2   = (const float*)d_in[9];
  const float* tb2   = (const float*)d_in[10];
  const float* tW3   = (const float*)d_in[11];
  const float* tb3   = (const float*)d_in[12];
  const float* l1Wih = (const float*)d_in[13];
  const float* l1Whh = (const float*)d_in[14];
  const float* l1bih = (const float*)d_in[15];
  const float* l1bhh = (const float*)d_in[16];
  const float* l2Wih = (const float*)d_in[17];
  const float* l2Whh = (const float*)d_in[18];
  const float* l2bih = (const float*)d_in[19];
  const float* l2bhh = (const float*)d_in[20];
  const float* mW    = (const float*)d_in[21];
  const float* mb    = (const float*)d_in[22];
  const float* lvW   = (const float*)d_in[23];
  const float* lvb   = (const float*)d_in[24];

  float* out = (float*)d_out;

  // workspace layout (acc doubles first, then float buffers; all 16B aligned)
  double* acc  = (double*)d_ws;
  float*  base = (float*)d_ws + 4;
  float* z     = base;                       // [BT, Z]
  float* p     = z    + (size_t)BT * Zd;     // [BT, Z]
  float* hidA  = p    + (size_t)BT * Zd;     // [BT, NF]
  float* hidB  = hidA + (size_t)BT * NF;     // [BT, NF]
  float* sbuf  = hidB + (size_t)BT * NF;     // [BT, Z]
  float* tbuf  = sbuf + (size_t)BT * Zd;     // [BT, Z]
  float* ldj   = tbuf + (size_t)BT * Zd;     // [BT]
  float* h1    = ldj  + BT;                  // [B, H] x4 contiguous
  float* c1    = h1   + (size_t)Bb * Hh;
  float* h2    = c1   + (size_t)Bb * Hh;
  float* c2    = h2   + (size_t)Bb * Hh;
  float* gates = c2   + (size_t)Bb * Hh;     // [B, 4H]
  float* meanb = gates + (size_t)Bb * 4 * Hh;// [B, Z]
  float* lvbuf = meanb + (size_t)Bb * Zd;    // [B, Z]

  hipMemsetAsync(acc, 0, 2 * sizeof(double), stream);
  hipMemsetAsync(ldj, 0, BT * sizeof(float), stream);
  hipMemsetAsync(h1, 0, 4 * (size_t)Bb * Hh * sizeof(float), stream);

  split_k<<<2048, 256, 0, stream>>>(nf, z, p);

  // ---- inverse flow: layers 8..0 ----
  const dim3 gMLP12(BT / BM, NF / BN);
  const dim3 gMLP3(BT / BM, Zd / BN);
  for (int i = NL - 1; i >= 0; --i) {
    const float* W1s = sW1 + (size_t)i * NF * (2 * Zd);
    const float* W2s = sW2 + (size_t)i * NF * NF;
    const float* W3s = sW3 + (size_t)i * Zd * NF;
    const float* W1t = tW1 + (size_t)i * NF * (2 * Zd);
    const float* W2t = tW2 + (size_t)i * NF * NF;
    const float* W3t = tW3 + (size_t)i * Zd * NF;

    gemm_k<AM_FLOW, EP_LEAKY><<<gMLP12, 256, 0, stream>>>(
        nullptr, 0, W1s, sb1 + i * NF, nullptr, hidA, NF, 2 * Zd, z, p, i);
    gemm_k<AM_DIRECT, EP_LEAKY><<<gMLP12, 256, 0, stream>>>(
        hidA, NF, W2s, sb2 + i * NF, nullptr, hidB, NF, NF, nullptr, nullptr, i);
    gemm_k<AM_DIRECT, EP_TANH_MASK><<<gMLP3, 256, 0, stream>>>(
        hidB, NF, W3s, sb3 + i * Zd, nullptr, sbuf, Zd, NF, nullptr, nullptr, i);

    gemm_k<AM_FLOW, EP_LEAKY><<<gMLP12, 256, 0, stream>>>(
        nullptr, 0, W1t, tb1 + i * NF, nullptr, hidA, NF, 2 * Zd, z, p, i);
    gemm_k<AM_DIRECT, EP_LEAKY><<<gMLP12, 256, 0, stream>>>(
        hidA, NF, W2t, tb2 + i * NF, nullptr, hidB, NF, NF, nullptr, nullptr, i);
    gemm_k<AM_DIRECT, EP_MASK><<<gMLP3, 256, 0, stream>>>(
        hidB, NF, W3t, tb3 + i * Zd, nullptr, tbuf, Zd, NF, nullptr, nullptr, i);

    flow_update_k<<<BT, 256, 0, stream>>>(z, sbuf, tbuf, ldj, i);
  }

  // ---- z3 output + logN(z3) + ldj sums ----
  z3_out_k<<<1024, 256, 0, stream>>>(z, out, acc);
  ldj_sum_k<<<64, 256, 0, stream>>>(ldj, acc);

  // ---- LSTM prior ----
  const dim3 gG(Bb / BM, (4 * Hh) / BN);   // 16 x 32
  const dim3 gMV(Bb / BM, Zd / BN);        // 16 x 4
  for (int t = 0; t < Tt; ++t) {
    const float* x = (t == 0) ? nullptr : (z + (size_t)(t - 1) * Zd); // row stride T*Z
    gemm_k<AM_DIRECT, EP_BIAS2><<<gG, 256, 0, stream>>>(
        x, Tt * Zd, l1Wih, l1bih, l1bhh, gates, 4 * Hh, Zd, nullptr, nullptr, 0);
    gemm_k<AM_DIRECT, EP_ACC><<<gG, 256, 0, stream>>>(
        h1, Hh, l1Whh, nullptr, nullptr, gates, 4 * Hh, Hh, nullptr, nullptr, 0);
    lstm_cell_k<<<(Bb * Hh) / 256, 256, 0, stream>>>(gates, h1, c1);

    gemm_k<AM_DIRECT, EP_BIAS2><<<gG, 256, 0, stream>>>(
        h1, Hh, l2Wih, l2bih, l2bhh, gates, 4 * Hh, Hh, nullptr, nullptr, 0);
    gemm_k<AM_DIRECT, EP_ACC><<<gG, 256, 0, stream>>>(
        h2, Hh, l2Whh, nullptr, nullptr, gates, 4 * Hh, Hh, nullptr, nullptr, 0);
    lstm_cell_k<<<(Bb * Hh) / 256, 256, 0, stream>>>(gates, h2, c2);

    gemm_k<AM_DIRECT, EP_BIAS><<<gMV, 256, 0, stream>>>(
        h2, Hh, mW, mb, nullptr, meanb, Zd, Hh, nullptr, nullptr, 0);
    gemm_k<AM_DIRECT, EP_BIAS><<<gMV, 256, 0, stream>>>(
        h2, Hh, lvW, lvb, nullptr, lvbuf, Zd, Hh, nullptr, nullptr, 0);
    post_k<<<Bb, 256, 0, stream>>>(meanb, lvbuf, z, t, acc);
  }

  finalize_k<<<1, 1, 0, stream>>>(acc, out);
}

// Round 4
// 2218.485 us; speedup vs baseline: 4.6928x; 4.6928x over previous
//
#include <hip/hip_runtime.h>
#include <math.h>

// ---------------- problem constants ----------------
constexpr int Zd = 256, Tt = 16, NF = 512, Hh = 512, NL = 9, Bb = 1024;
constexpr int BT = Bb * Tt; // 16384
constexpr float LOG_SQRT_2PI_F = 0.9189385332046727f;

typedef _Float16 f16;
typedef __attribute__((ext_vector_type(8))) _Float16 f16x8;
typedef __attribute__((ext_vector_type(4))) float f32x4;

__device__ __forceinline__ bool maskbit(int layer, int k) {
  if (layer == 0) return false;
  return (layer & 1) ? ((k & 1) != 0) : ((k & 1) == 0);
}

__device__ __forceinline__ void gld16(void* lds, const void* g) {
  __builtin_amdgcn_global_load_lds(
      (const __attribute__((address_space(1))) void*)g,
      (__attribute__((address_space(3))) void*)lds, 16, 0, 0);
}

enum { EPI_LEAKY = 0, EPI_S = 1, EPI_T = 2, EPI_GATES = 3, EPI_MV = 4 };

// C[M,N] = epi(A[M,K(lda)] @ W[N,K]^T), fp16 inputs, fp32 MFMA accum.
// 128x128 tile, BK=32, 256 thr = 4 waves, m97 2-barrier structure.
template <int EPI>
__global__ __launch_bounds__(256)
void hgemm_k(const f16* __restrict__ A, int lda,
             const f16* __restrict__ W, int K,
             const float* __restrict__ bias, const float* __restrict__ bias2,
             void* __restrict__ C0, int ldc, int layer)
{
  __shared__ f16 As[128][32];
  __shared__ f16 Bs[128][32];
  const int bm = blockIdx.x * 128;
  const int bn = blockIdx.y * 128;
  const int tid = threadIdx.x;
  const int lane = tid & 63;
  const int wid = tid >> 6;
  const int wr = (wid >> 1) * 64;
  const int wc = (wid & 1) * 64;
  const int l15 = lane & 15;
  const int l4 = lane >> 4;      // 0..3
  const int arow = tid >> 2;     // 0..63
  const int akb = (tid & 3) * 16;

  f32x4 acc[4][4] = {};

  for (int k0 = 0; k0 < K; k0 += 32) {
    __syncthreads();
    gld16((char*)As + tid * 16,
          (const char*)A + ((size_t)(bm + arow) * lda + k0) * 2 + akb);
    gld16((char*)As + (tid + 256) * 16,
          (const char*)A + ((size_t)(bm + 64 + arow) * lda + k0) * 2 + akb);
    gld16((char*)Bs + tid * 16,
          (const char*)W + ((size_t)(bn + arow) * K + k0) * 2 + akb);
    gld16((char*)Bs + (tid + 256) * 16,
          (const char*)W + ((size_t)(bn + 64 + arow) * K + k0) * 2 + akb);
    __syncthreads();
    f16x8 af[4], bf[4];
#pragma unroll
    for (int i = 0; i < 4; ++i) af[i] = *(const f16x8*)&As[wr + 16 * i + l15][l4 * 8];
#pragma unroll
    for (int j = 0; j < 4; ++j) bf[j] = *(const f16x8*)&Bs[wc + 16 * j + l15][l4 * 8];
#pragma unroll
    for (int i = 0; i < 4; ++i)
#pragma unroll
      for (int j = 0; j < 4; ++j)
        acc[i][j] = __builtin_amdgcn_mfma_f32_16x16x32_f16(af[i], bf[j], acc[i][j], 0, 0, 0);
  }

#pragma unroll
  for (int i = 0; i < 4; ++i) {
    const int row0 = bm + wr + 16 * i + l4 * 4;
#pragma unroll
    for (int j = 0; j < 4; ++j) {
      const int col = bn + wc + 16 * j + l15;
#pragma unroll
      for (int r = 0; r < 4; ++r) {
        float v = acc[i][j][r];
        const size_t ci = (size_t)(row0 + r) * ldc + col;
        if (EPI == EPI_LEAKY) {
          v += bias[col];
          v = v > 0.f ? v : 0.01f * v;
          ((f16*)C0)[ci] = (f16)v;
        } else if (EPI == EPI_S) {
          v = tanhf(v + bias[col]);
          if (maskbit(layer, col)) v = 0.f;
          ((f16*)C0)[ci] = (f16)v;
        } else if (EPI == EPI_T) {
          v += bias[col];
          if (maskbit(layer, col)) v = 0.f;
          ((f16*)C0)[ci] = (f16)v;
        } else if (EPI == EPI_GATES) {
          ((float*)C0)[ci] = v + bias[col] + bias2[col];
        } else { // EPI_MV
          ((f16*)C0)[ci] = (f16)(v + bias[col]);
        }
      }
    }
  }
}

// ---------------- elementwise / reductions ----------------

__device__ __forceinline__ double block_reduce_d(double v) {
  __shared__ double sred[4];
#pragma unroll
  for (int off = 32; off > 0; off >>= 1) v += __shfl_down(v, off);
  const int lane = threadIdx.x & 63;
  const int w = threadIdx.x >> 6;
  if (lane == 0) sred[w] = v;
  __syncthreads();
  double r = 0.0;
  if (threadIdx.x == 0) {
    const int nw = blockDim.x >> 6;
    r = sred[0];
    for (int i = 1; i < nw; ++i) r += sred[i];
  }
  return r;
}

// z fp32, inp p-half, inp z-half masked for layer 8 (even k kept)
__global__ __launch_bounds__(256)
void split_k(const float* __restrict__ nf, float* __restrict__ z, f16* __restrict__ inp) {
  const int n = BT * Zd;
  for (int i = blockIdx.x * blockDim.x + threadIdx.x; i < n; i += gridDim.x * blockDim.x) {
    const int m = i >> 8, k = i & 255;
    const float pv = nf[(size_t)m * 512 + k];
    const float zv = nf[(size_t)m * 512 + 256 + k];
    z[(size_t)m * 256 + k] = zv;
    inp[(size_t)m * 512 + 256 + k] = (f16)pv;
    inp[(size_t)m * 512 + k] = ((k & 1) == 0) ? (f16)zv : (f16)0.f;
  }
}

// z update + ldj + write next layer's masked-z input half (nextlayer > 0)
__global__ __launch_bounds__(256)
void flow_update_k(float* __restrict__ z, const f16* __restrict__ s16,
                   const f16* __restrict__ t16, float* __restrict__ ldj,
                   f16* __restrict__ inp, int layer, int nextlayer) {
  const int m = blockIdx.x, k = threadIdx.x;
  const size_t idx = (size_t)m * 256 + k;
  const float sv = (float)s16[idx];
  const float tv = (float)t16[idx];
  const float zv = z[idx];
  const float zn = maskbit(layer, k) ? zv : (zv - tv) * expf(-sv);
  z[idx] = zn;
  if (nextlayer > 0)
    inp[(size_t)m * 512 + k] = maskbit(nextlayer, k) ? (f16)zn : (f16)0.f;
  __shared__ float red[256];
  red[k] = sv;
  __syncthreads();
  for (int off = 128; off > 0; off >>= 1) {
    if (k < off) red[k] += red[k + off];
    __syncthreads();
  }
  if (k == 0) ldj[m] -= red[0];
}

// layer-0 input: z_shift
__global__ __launch_bounds__(256)
void prep0_k(const float* __restrict__ z, f16* __restrict__ inp) {
  const int n = BT * Zd;
  for (int i = blockIdx.x * blockDim.x + threadIdx.x; i < n; i += gridDim.x * blockDim.x) {
    const int m = i >> 8, k = i & 255;
    const float v = ((m & 15) == 0) ? 0.f : z[(size_t)(m - 1) * 256 + k];
    inp[(size_t)m * 512 + k] = (f16)v;
  }
}

__global__ __launch_bounds__(256)
void z3_out_k(const float* __restrict__ z, float* __restrict__ out, double* __restrict__ acc) {
  const int n = BT * Zd;
  double local = 0.0;
  for (int i = blockIdx.x * blockDim.x + threadIdx.x; i < n; i += gridDim.x * blockDim.x) {
    const float v = z[i];
    out[1 + i] = v;
    local += (double)(-0.5f * v * v - LOG_SQRT_2PI_F);
  }
  local = block_reduce_d(local);
  if (threadIdx.x == 0) atomicAdd(acc + 1, local);
}

__global__ __launch_bounds__(256)
void ldj_sum_k(const float* __restrict__ ldj, double* __restrict__ acc) {
  double local = 0.0;
  for (int i = blockIdx.x * blockDim.x + threadIdx.x; i < BT; i += gridDim.x * blockDim.x)
    local += (double)ldj[i];
  local = block_reduce_d(local);
  if (threadIdx.x == 0) atomicAdd(acc + 1, local);
}

// x-halves of cbuf1 for all t: x_t = z[b][t-1] (0 at t=0)
__global__ __launch_bounds__(256)
void xfill_k(const float* __restrict__ z, f16* __restrict__ cbuf1) {
  const int n = Tt * Bb * Zd;
  for (int i = blockIdx.x * blockDim.x + threadIdx.x; i < n; i += gridDim.x * blockDim.x) {
    const int k = i & 255;
    const int b = (i >> 8) & 1023;
    const int t = i >> 18;
    const float v = (t == 0) ? 0.f : z[((size_t)b * 16 + (t - 1)) * 256 + k];
    cbuf1[((size_t)t * 1024 + b) * 768 + k] = (f16)v;
  }
}

// cell1: h1 -> cbuf2[:, 0:512] and cbuf1[t+1][:, 256:768]
__global__ __launch_bounds__(256)
void cell1_k(const float* __restrict__ g, float* __restrict__ c,
             f16* __restrict__ cbuf2, f16* __restrict__ cbuf1, int t) {
  const int idx = blockIdx.x * 256 + threadIdx.x; // < 1024*512
  const int b = idx >> 9, j = idx & 511;
  const float* gm = g + (size_t)b * 2048;
  const float gi = gm[j], gf = gm[512 + j], gg = gm[1024 + j], go = gm[1536 + j];
  const float si = 1.f / (1.f + expf(-gi));
  const float sf = 1.f / (1.f + expf(-gf));
  const float so = 1.f / (1.f + expf(-go));
  const float cv = sf * c[idx] + si * tanhf(gg);
  const float h = so * tanhf(cv);
  c[idx] = cv;
  cbuf2[(size_t)b * 1024 + j] = (f16)h;
  if (t + 1 < Tt) cbuf1[((size_t)(t + 1) * 1024 + b) * 768 + 256 + j] = (f16)h;
}

// cell2: h2 -> cbuf2[:, 512:1024] and hall[t*1024+b]
__global__ __launch_bounds__(256)
void cell2_k(const float* __restrict__ g, float* __restrict__ c,
             f16* __restrict__ cbuf2, f16* __restrict__ hall, int t) {
  const int idx = blockIdx.x * 256 + threadIdx.x;
  const int b = idx >> 9, j = idx & 511;
  const float* gm = g + (size_t)b * 2048;
  const float gi = gm[j], gf = gm[512 + j], gg = gm[1024 + j], go = gm[1536 + j];
  const float si = 1.f / (1.f + expf(-gi));
  const float sf = 1.f / (1.f + expf(-gf));
  const float so = 1.f / (1.f + expf(-go));
  const float cv = sf * c[idx] + si * tanhf(gg);
  const float h = so * tanhf(cv);
  c[idx] = cv;
  cbuf2[(size_t)b * 1024 + 512 + j] = (f16)h;
  hall[((size_t)t * 1024 + b) * 512 + j] = (f16)h;
}

// sum over all (t,b,k): logN((z3-mean)*exp(-lv)) - lv  -> acc[0]
__global__ __launch_bounds__(256)
void post_all_k(const f16* __restrict__ mv, const float* __restrict__ z,
                double* __restrict__ acc) {
  const int n = BT * Zd;
  double local = 0.0;
  for (int i = blockIdx.x * blockDim.x + threadIdx.x; i < n; i += gridDim.x * blockDim.x) {
    const int k = i & 255;
    const int row = i >> 8;               // t*1024 + b
    const int t = row >> 10, b = row & 1023;
    const float mean = (float)mv[(size_t)row * 512 + k];
    const float lv = (float)mv[(size_t)row * 512 + 256 + k];
    const float zv = z[((size_t)b * 16 + t) * 256 + k];
    const float d = (zv - mean) * expf(-lv);
    local += (double)(-0.5f * d * d - LOG_SQRT_2PI_F) - (double)lv;
  }
  local = block_reduce_d(local);
  if (threadIdx.x == 0) atomicAdd(acc + 0, local);
}

__global__ void finalize_k(const double* __restrict__ acc, float* __restrict__ out) {
  const double loglik = 0.0025 * acc[0] + acc[1];
  out[0] = (float)(-loglik / (double)Bb);
}

// ---------------- weight conversion ----------------
__global__ __launch_bounds__(256)
void cvt_k(const float* __restrict__ s, f16* __restrict__ d, int n) {
  for (int i = blockIdx.x * blockDim.x + threadIdx.x; i < n; i += gridDim.x * blockDim.x)
    d[i] = (f16)s[i];
}

// dst[l][2R][K]: rows<R from a[l], else b[l]
__global__ __launch_bounds__(256)
void cvt_cat_rows_k(const float* __restrict__ a, const float* __restrict__ b,
                    f16* __restrict__ d, int L, int R, int K) {
  const int n = L * 2 * R * K;
  for (int i = blockIdx.x * blockDim.x + threadIdx.x; i < n; i += gridDim.x * blockDim.x) {
    const int k = i % K;
    const int rem = i / K;
    const int r = rem % (2 * R);
    const int l = rem / (2 * R);
    const float v = (r < R) ? a[((size_t)l * R + r) * K + k]
                            : b[((size_t)l * R + (r - R)) * K + k];
    d[i] = (f16)v;
  }
}

// dst[R][KA+KB]: cols<KA from a, else b
__global__ __launch_bounds__(256)
void cvt_cat_cols_k(const float* __restrict__ a, int KA, const float* __restrict__ b,
                    int KB, f16* __restrict__ d, int R) {
  const int n = R * (KA + KB);
  for (int i = blockIdx.x * blockDim.x + threadIdx.x; i < n; i += gridDim.x * blockDim.x) {
    const int c = i % (KA + KB);
    const int r = i / (KA + KB);
    const float v = (c < KA) ? a[(size_t)r * KA + c] : b[(size_t)r * KB + (c - KA)];
    d[i] = (f16)v;
  }
}

// fp32 concat per layer: dst[l][2R] = [a[l] | b[l]]
__global__ __launch_bounds__(256)
void fcat_k(const float* __restrict__ a, const float* __restrict__ b,
            float* __restrict__ d, int L, int R) {
  const int n = L * 2 * R;
  for (int i = blockIdx.x * blockDim.x + threadIdx.x; i < n; i += gridDim.x * blockDim.x) {
    const int c = i % (2 * R);
    const int l = i / (2 * R);
    d[i] = (c < R) ? a[(size_t)l * R + c] : b[(size_t)l * R + (c - R)];
  }
}

// ---------------- host launch ----------------
extern "C" void kernel_launch(void* const* d_in, const int* in_sizes, int n_in,
                              void* d_out, int out_size, void* d_ws, size_t ws_size,
                              hipStream_t stream) {
  (void)in_sizes; (void)n_in; (void)out_size; (void)ws_size;

  const float* nf    = (const float*)d_in[0];
  const float* sW1   = (const float*)d_in[1];
  const float* sb1   = (const float*)d_in[2];
  const float* sW2   = (const float*)d_in[3];
  const float* sb2   = (const float*)d_in[4];
  const float* sW3   = (const float*)d_in[5];
  const float* sb3   = (const float*)d_in[6];
  const float* tW1   = (const float*)d_in[7];
  const float* tb1   = (const float*)d_in[8];
  const float* tW2   = (const float*)d_in[9];
  const float* tb2   = (const float*)d_in[10];
  const float* tW3   = (const float*)d_in[11];
  const float* tb3   = (const float*)d_in[12];
  const float* l1Wih = (const float*)d_in[13];
  const float* l1Whh = (const float*)d_in[14];
  const float* l1bih = (const float*)d_in[15];
  const float* l1bhh = (const float*)d_in[16];
  const float* l2Wih = (const float*)d_in[17];
  const float* l2Whh = (const float*)d_in[18];
  const float* l2bih = (const float*)d_in[19];
  const float* l2bhh = (const float*)d_in[20];
  const float* mW    = (const float*)d_in[21];
  const float* mb    = (const float*)d_in[22];
  const float* lvW   = (const float*)d_in[23];
  const float* lvb   = (const float*)d_in[24];

  float* out = (float*)d_out;

  char* wsb = (char*)d_ws;
  size_t off = 0;
  auto alloc = [&](size_t bytes) -> char* {
    char* p = wsb + off;
    off += (bytes + 255) & ~(size_t)255;
    return p;
  };
  double* acc  = (double*)alloc(16);
  float*  z    = (float*)alloc((size_t)BT * Zd * 4);         // 16 MB
  f16*    inp  = (f16*)alloc((size_t)BT * 512 * 2);          // 16 MB (LSTM: mvbuf)
  f16*    hidA = (f16*)alloc((size_t)BT * 1024 * 2);         // 32 MB (LSTM: cbuf1+cbuf2)
  f16*    hidB = (f16*)alloc((size_t)BT * 1024 * 2);         // 32 MB (LSTM: hall+gates)
  f16*    s16  = (f16*)alloc((size_t)BT * Zd * 2);           // 8 MB (LSTM: c1,c2)
  f16*    t16  = (f16*)alloc((size_t)BT * Zd * 2);           // 8 MB
  float*  ldj  = (float*)alloc((size_t)BT * 4);
  f16* w1cat = (f16*)alloc((size_t)9 * 1024 * 512 * 2);
  f16* w2s   = (f16*)alloc((size_t)9 * 512 * 512 * 2);
  f16* w2t   = (f16*)alloc((size_t)9 * 512 * 512 * 2);
  f16* w3s   = (f16*)alloc((size_t)9 * 256 * 512 * 2);
  f16* w3t   = (f16*)alloc((size_t)9 * 256 * 512 * 2);
  f16* wcat1 = (f16*)alloc((size_t)2048 * 768 * 2);
  f16* wcat2 = (f16*)alloc((size_t)2048 * 1024 * 2);
  f16* wmv   = (f16*)alloc((size_t)512 * 512 * 2);
  float* bcat1 = (float*)alloc((size_t)9 * 1024 * 4);
  float* bmv   = (float*)alloc((size_t)512 * 4);

  // LSTM-phase aliases (flow buffers dead by then)
  f16*   cbuf1 = hidA;                                   // [16][1024][768]
  f16*   cbuf2 = hidA + (size_t)16 * 1024 * 768;         // [1024][1024]
  f16*   hall  = hidB;                                   // [16384][512]
  float* gates = (float*)(hidB + (size_t)BT * 512);      // [1024][2048] fp32
  float* c1    = (float*)s16;                            // [1024][512] fp32
  float* c2    = (float*)s16 + (size_t)Bb * Hh;
  f16*   mvbuf = inp;                                    // [16384][512]

  // ---- weight conversions ----
  cvt_cat_rows_k<<<2048, 256, 0, stream>>>(sW1, tW1, w1cat, 9, 512, 512);
  cvt_k<<<2048, 256, 0, stream>>>(sW2, w2s, 9 * 512 * 512);
  cvt_k<<<2048, 256, 0, stream>>>(tW2, w2t, 9 * 512 * 512);
  cvt_k<<<1024, 256, 0, stream>>>(sW3, w3s, 9 * 256 * 512);
  cvt_k<<<1024, 256, 0, stream>>>(tW3, w3t, 9 * 256 * 512);
  cvt_cat_cols_k<<<1024, 256, 0, stream>>>(l1Wih, 256, l1Whh, 512, wcat1, 2048);
  cvt_cat_cols_k<<<1024, 256, 0, stream>>>(l2Wih, 512, l2Whh, 512, wcat2, 2048);
  cvt_cat_rows_k<<<256, 256, 0, stream>>>(mW, lvW, wmv, 1, 256, 512);
  fcat_k<<<16, 256, 0, stream>>>(sb1, tb1, bcat1, 9, 512);
  fcat_k<<<2, 256, 0, stream>>>(mb, lvb, bmv, 1, 256);

  hipMemsetAsync(acc, 0, 16, stream);
  hipMemsetAsync(ldj, 0, (size_t)BT * 4, stream);

  split_k<<<2048, 256, 0, stream>>>(nf, z, inp);

  // ---- inverse flow: layers 8..0 ----
  for (int i = NL - 1; i >= 0; --i) {
    hgemm_k<EPI_LEAKY><<<dim3(128, 8), 256, 0, stream>>>(
        inp, 512, w1cat + (size_t)i * 1024 * 512, 512, bcat1 + i * 1024, nullptr,
        hidA, 1024, 0);
    hgemm_k<EPI_LEAKY><<<dim3(128, 4), 256, 0, stream>>>(
        hidA, 1024, w2s + (size_t)i * 512 * 512, 512, sb2 + i * 512, nullptr,
        hidB, 1024, 0);
    hgemm_k<EPI_LEAKY><<<dim3(128, 4), 256, 0, stream>>>(
        hidA + 512, 1024, w2t + (size_t)i * 512 * 512, 512, tb2 + i * 512, nullptr,
        hidB + 512, 1024, 0);
    hgemm_k<EPI_S><<<dim3(128, 2), 256, 0, stream>>>(
        hidB, 1024, w3s + (size_t)i * 256 * 512, 512, sb3 + i * 256, nullptr,
        s16, 256, i);
    hgemm_k<EPI_T><<<dim3(128, 2), 256, 0, stream>>>(
        hidB + 512, 1024, w3t + (size_t)i * 256 * 512, 512, tb3 + i * 256, nullptr,
        t16, 256, i);
    flow_update_k<<<BT, 256, 0, stream>>>(z, s16, t16, ldj, inp, i, i - 1);
    if (i - 1 == 0) prep0_k<<<2048, 256, 0, stream>>>(z, inp);
  }

  z3_out_k<<<1024, 256, 0, stream>>>(z, out, acc);
  ldj_sum_k<<<64, 256, 0, stream>>>(ldj, acc);

  // ---- LSTM prior ----
  hipMemsetAsync(cbuf1, 0, (size_t)1024 * 768 * 2, stream);        // t=0 slab
  hipMemsetAsync(cbuf2, 0, (size_t)1024 * 1024 * 2, stream);
  hipMemsetAsync(c1, 0, (size_t)Bb * Hh * 4, stream);
  hipMemsetAsync(c2, 0, (size_t)Bb * Hh * 4, stream);
  xfill_k<<<2048, 256, 0, stream>>>(z, cbuf1);

  for (int t = 0; t < Tt; ++t) {
    hgemm_k<EPI_GATES><<<dim3(8, 16), 256, 0, stream>>>(
        cbuf1 + (size_t)t * 1024 * 768, 768, wcat1, 768, l1bih, l1bhh,
        gates, 2048, 0);
    cell1_k<<<2048, 256, 0, stream>>>(gates, c1, cbuf2, cbuf1, t);
    hgemm_k<EPI_GATES><<<dim3(8, 16), 256, 0, stream>>>(
        cbuf2, 1024, wcat2, 1024, l2bih, l2bhh, gates, 2048, 0);
    cell2_k<<<2048, 256, 0, stream>>>(gates, c2, cbuf2, hall, t);
  }

  hgemm_k<EPI_MV><<<dim3(128, 4), 256, 0, stream>>>(
      hall, 512, wmv, 512, bmv, nullptr, mvbuf, 512, 0);
  post_all_k<<<1024, 256, 0, stream>>>(mvbuf, z, acc);

  finalize_k<<<1, 1, 0, stream>>>(acc, out);
}

// Round 5
// 1616.440 us; speedup vs baseline: 6.4407x; 1.3725x over previous
//
#include <hip/hip_runtime.h>
#include <math.h>

// ---------------- problem constants ----------------
constexpr int Zd = 256, Tt = 16, NF = 512, Hh = 512, NL = 9, Bb = 1024;
constexpr int BT = Bb * Tt; // 16384
constexpr float LOG_SQRT_2PI_F = 0.9189385332046727f;

typedef _Float16 f16;
typedef __attribute__((ext_vector_type(4))) _Float16 f16x4;
typedef __attribute__((ext_vector_type(8))) _Float16 f16x8;
typedef __attribute__((ext_vector_type(4))) float f32x4;

__device__ __forceinline__ bool maskbit(int layer, int k) {
  if (layer == 0) return false;
  return (layer & 1) ? ((k & 1) != 0) : ((k & 1) == 0);
}

__device__ __forceinline__ void gld16(void* lds, const void* g) {
  __builtin_amdgcn_global_load_lds(
      (const __attribute__((address_space(1))) void*)g,
      (__attribute__((address_space(3))) void*)lds, 16, 0, 0);
}

__device__ __forceinline__ float fsig(float x) {
  return __builtin_amdgcn_rcpf(1.f + __expf(-x));
}
__device__ __forceinline__ float ftanhf(float x) {
  const float e = __expf(2.f * x);
  return 1.f - 2.f * __builtin_amdgcn_rcpf(e + 1.f);
}

enum { EPI_LEAKY = 0, EPI_S = 1, EPI_T = 2, EPI_MV = 3 };

template <int EPI>
__device__ __forceinline__ void epilogue128(const f32x4 (&acc)[4][4],
                                            const float* __restrict__ bias,
                                            void* __restrict__ C0, int ldc,
                                            int layer, int bm, int bn, int wr,
                                            int wc, int l15, int l4) {
#pragma unroll
  for (int i = 0; i < 4; ++i) {
    const int row0 = bm + wr + 16 * i + l4 * 4;
#pragma unroll
    for (int j = 0; j < 4; ++j) {
      const int col = bn + wc + 16 * j + l15;
#pragma unroll
      for (int r = 0; r < 4; ++r) {
        float v = acc[i][j][r];
        const size_t ci = (size_t)(row0 + r) * ldc + col;
        if (EPI == EPI_LEAKY) {
          v += bias[col];
          v = v > 0.f ? v : 0.01f * v;
          ((f16*)C0)[ci] = (f16)v;
        } else if (EPI == EPI_S) {
          v = ftanhf(v + bias[col]);
          if (maskbit(layer, col)) v = 0.f;
          ((f16*)C0)[ci] = (f16)v;
        } else if (EPI == EPI_T) {
          v += bias[col];
          if (maskbit(layer, col)) v = 0.f;
          ((f16*)C0)[ci] = (f16)v;
        } else { // EPI_MV
          ((f16*)C0)[ci] = (f16)(v + bias[col]);
        }
      }
    }
  }
}

// Dual GEMM: blockIdx.z selects parameter set. C = epi(A[M,K(lda)] @ W[N,K]^T)
// 128x128 tile, BK=32, 4 waves, 2-phase prefetch double-buffered LDS.
template <int EPI0, int EPI1>
__global__ __launch_bounds__(256, 4)
void hgemm2_k(const f16* __restrict__ A0, const f16* __restrict__ A1, int lda,
              const f16* __restrict__ W0, const f16* __restrict__ W1, int K,
              const float* __restrict__ b0, const float* __restrict__ b1,
              void* __restrict__ C0v, void* __restrict__ C1v, int ldc, int layer)
{
  __shared__ f16 As[2][128][32];
  __shared__ f16 Bs[2][128][32];
  const int zsel = blockIdx.z;
  const f16* A = zsel ? A1 : A0;
  const f16* W = zsel ? W1 : W0;
  const float* bias = zsel ? b1 : b0;
  void* Cv = zsel ? C1v : C0v;

  const int bm = blockIdx.x * 128;
  const int bn = blockIdx.y * 128;
  const int tid = threadIdx.x;
  const int lane = tid & 63;
  const int wid = tid >> 6;
  const int wr = (wid >> 1) * 64;
  const int wc = (wid & 1) * 64;
  const int l15 = lane & 15;
  const int l4 = lane >> 4;
  const int arow = tid >> 2;
  const int akb = (tid & 3) * 16;

  const char* Ab = (const char*)A + (size_t)(bm + arow) * lda * 2 + akb;
  const char* Wb = (const char*)W + (size_t)(bn + arow) * K * 2 + akb;

  auto stage = [&](int buf, int k0) {
    const size_t kb = (size_t)k0 * 2;
    char* la = (char*)&As[buf][0][0];
    char* lb = (char*)&Bs[buf][0][0];
    gld16(la + tid * 16, Ab + kb);
    gld16(la + 4096 + tid * 16, Ab + kb + (size_t)lda * 128);
    gld16(lb + tid * 16, Wb + kb);
    gld16(lb + 4096 + tid * 16, Wb + kb + (size_t)K * 128);
  };

  f32x4 acc[4][4] = {};
  const int nk = K >> 5;
  stage(0, 0);
  __syncthreads();

  for (int t = 0; t < nk; ++t) {
    const int cur = t & 1;
    if (t + 1 < nk) stage(cur ^ 1, (t + 1) << 5);
    f16x8 af[4], bf[4];
#pragma unroll
    for (int i = 0; i < 4; ++i) af[i] = *(const f16x8*)&As[cur][wr + 16 * i + l15][l4 * 8];
#pragma unroll
    for (int j = 0; j < 4; ++j) bf[j] = *(const f16x8*)&Bs[cur][wc + 16 * j + l15][l4 * 8];
#pragma unroll
    for (int i = 0; i < 4; ++i)
#pragma unroll
      for (int j = 0; j < 4; ++j)
        acc[i][j] = __builtin_amdgcn_mfma_f32_16x16x32_f16(af[i], bf[j], acc[i][j], 0, 0, 0);
    __syncthreads();  // drains vmcnt (prefetch) + lgkm (ds_reads)
  }

  if (zsel == 0)
    epilogue128<EPI0>(acc, bias, Cv, ldc, layer, bm, bn, wr, wc, l15, l4);
  else
    epilogue128<EPI1>(acc, bias, Cv, ldc, layer, bm, bn, wr, wc, l15, l4);
}

// 64x64-tile GEMM for LSTM gates: C fp32 = A @ W^T + bih + bhh. 4 waves,
// wave w owns 16 cols; 2-phase prefetch.
__global__ __launch_bounds__(256, 4)
void hgemm64_k(const f16* __restrict__ A, int lda,
               const f16* __restrict__ W, int K,
               const float* __restrict__ bias, const float* __restrict__ bias2,
               float* __restrict__ C, int ldc)
{
  __shared__ f16 As[2][64][32];
  __shared__ f16 Bs[2][64][32];
  const int bm = blockIdx.x * 64;
  const int bn = blockIdx.y * 64;
  const int tid = threadIdx.x;
  const int lane = tid & 63;
  const int wid = tid >> 6;
  const int l15 = lane & 15;
  const int l4 = lane >> 4;
  const int lr = tid >> 2;
  const int lk = (tid & 3) * 16;

  const char* Ab = (const char*)A + (size_t)(bm + lr) * lda * 2 + lk;
  const char* Wb = (const char*)W + (size_t)(bn + lr) * K * 2 + lk;

  auto stage = [&](int buf, int k0) {
    const size_t kb = (size_t)k0 * 2;
    gld16((char*)&As[buf][0][0] + tid * 16, Ab + kb);
    gld16((char*)&Bs[buf][0][0] + tid * 16, Wb + kb);
  };

  f32x4 acc[4] = {};
  const int nk = K >> 5;
  stage(0, 0);
  __syncthreads();

  for (int t = 0; t < nk; ++t) {
    const int cur = t & 1;
    if (t + 1 < nk) stage(cur ^ 1, (t + 1) << 5);
    f16x8 af[4], bf;
#pragma unroll
    for (int i = 0; i < 4; ++i) af[i] = *(const f16x8*)&As[cur][16 * i + l15][l4 * 8];
    bf = *(const f16x8*)&Bs[cur][wid * 16 + l15][l4 * 8];
#pragma unroll
    for (int i = 0; i < 4; ++i)
      acc[i] = __builtin_amdgcn_mfma_f32_16x16x32_f16(af[i], bf, acc[i], 0, 0, 0);
    __syncthreads();
  }

  const int col = bn + wid * 16 + l15;
  const float bb = bias[col] + bias2[col];
#pragma unroll
  for (int i = 0; i < 4; ++i) {
    const int row0 = bm + 16 * i + l4 * 4;
#pragma unroll
    for (int r = 0; r < 4; ++r)
      C[(size_t)(row0 + r) * ldc + col] = acc[i][r] + bb;
  }
}

// ---------------- elementwise / reductions ----------------

__device__ __forceinline__ double block_reduce_d(double v) {
  __shared__ double sred[4];
#pragma unroll
  for (int off = 32; off > 0; off >>= 1) v += __shfl_down(v, off);
  const int lane = threadIdx.x & 63;
  const int w = threadIdx.x >> 6;
  if (lane == 0) sred[w] = v;
  __syncthreads();
  double r = 0.0;
  if (threadIdx.x == 0) {
    const int nw = blockDim.x >> 6;
    r = sred[0];
    for (int i = 1; i < nw; ++i) r += sred[i];
  }
  return r;
}

__global__ __launch_bounds__(256)
void split_k(const float* __restrict__ nf, float* __restrict__ z, f16* __restrict__ inp) {
  const int n = BT * Zd;
  for (int i = blockIdx.x * blockDim.x + threadIdx.x; i < n; i += gridDim.x * blockDim.x) {
    const int m = i >> 8, k = i & 255;
    const float pv = nf[(size_t)m * 512 + k];
    const float zv = nf[(size_t)m * 512 + 256 + k];
    z[(size_t)m * 256 + k] = zv;
    inp[(size_t)m * 512 + 256 + k] = (f16)pv;
    inp[(size_t)m * 512 + k] = ((k & 1) == 0) ? (f16)zv : (f16)0.f;
  }
}

// one wave per row (4 rows/block): z update + ldj + next-layer masked-z input
__global__ __launch_bounds__(256)
void flow_update_k(float* __restrict__ z, const f16* __restrict__ s16,
                   const f16* __restrict__ t16, float* __restrict__ ldj,
                   f16* __restrict__ inp, int layer, int nextlayer) {
  const int w = threadIdx.x >> 6, lane = threadIdx.x & 63;
  const int m = blockIdx.x * 4 + w;
  const int k0 = lane * 4;
  const size_t base = (size_t)m * 256 + k0;
  const float4 zv = *(const float4*)(z + base);
  const f16x4 sv = *(const f16x4*)(s16 + base);
  const f16x4 tv = *(const f16x4*)(t16 + base);
  float zr[4] = {zv.x, zv.y, zv.z, zv.w};
  float ssum = 0.f;
  float zn[4];
#pragma unroll
  for (int e = 0; e < 4; ++e) {
    const float s = (float)sv[e];
    ssum += s;
    zn[e] = maskbit(layer, k0 + e) ? zr[e] : (zr[e] - (float)tv[e]) * __expf(-s);
  }
  *(float4*)(z + base) = make_float4(zn[0], zn[1], zn[2], zn[3]);
  if (nextlayer > 0) {
    f16x4 o;
#pragma unroll
    for (int e = 0; e < 4; ++e)
      o[e] = maskbit(nextlayer, k0 + e) ? (f16)zn[e] : (f16)0.f;
    *(f16x4*)(inp + (size_t)m * 512 + k0) = o;
  }
#pragma unroll
  for (int off = 32; off > 0; off >>= 1) ssum += __shfl_down(ssum, off);
  if (lane == 0) ldj[m] -= ssum;
}

// layer-0 input: z_shift
__global__ __launch_bounds__(256)
void prep0_k(const float* __restrict__ z, f16* __restrict__ inp) {
  const int n = BT * Zd;
  for (int i = blockIdx.x * blockDim.x + threadIdx.x; i < n; i += gridDim.x * blockDim.x) {
    const int m = i >> 8, k = i & 255;
    const float v = ((m & 15) == 0) ? 0.f : z[(size_t)(m - 1) * 256 + k];
    inp[(size_t)m * 512 + k] = (f16)v;
  }
}

__global__ __launch_bounds__(256)
void z3_out_k(const float* __restrict__ z, float* __restrict__ out, double* __restrict__ acc) {
  const int n = BT * Zd;
  double local = 0.0;
  for (int i = blockIdx.x * blockDim.x + threadIdx.x; i < n; i += gridDim.x * blockDim.x) {
    const float v = z[i];
    out[1 + i] = v;
    local += (double)(-0.5f * v * v - LOG_SQRT_2PI_F);
  }
  local = block_reduce_d(local);
  if (threadIdx.x == 0) atomicAdd(acc + 1, local);
}

__global__ __launch_bounds__(256)
void ldj_sum_k(const float* __restrict__ ldj, double* __restrict__ acc) {
  double local = 0.0;
  for (int i = blockIdx.x * blockDim.x + threadIdx.x; i < BT; i += gridDim.x * blockDim.x)
    local += (double)ldj[i];
  local = block_reduce_d(local);
  if (threadIdx.x == 0) atomicAdd(acc + 1, local);
}

// x-halves of cbuf1 for all t: x_t = z[b][t-1] (0 at t=0)
__global__ __launch_bounds__(256)
void xfill_k(const float* __restrict__ z, f16* __restrict__ cbuf1) {
  const int n = Tt * Bb * Zd;
  for (int i = blockIdx.x * blockDim.x + threadIdx.x; i < n; i += gridDim.x * blockDim.x) {
    const int k = i & 255;
    const int b = (i >> 8) & 1023;
    const int t = i >> 18;
    const float v = (t == 0) ? 0.f : z[((size_t)b * 16 + (t - 1)) * 256 + k];
    cbuf1[((size_t)t * 1024 + b) * 768 + k] = (f16)v;
  }
}

__global__ __launch_bounds__(256)
void cell1_k(const float* __restrict__ g, float* __restrict__ c,
             f16* __restrict__ cbuf2, f16* __restrict__ cbuf1, int t) {
  const int idx = blockIdx.x * 256 + threadIdx.x;
  const int b = idx >> 9, j = idx & 511;
  const float* gm = g + (size_t)b * 2048;
  const float gi = gm[j], gf = gm[512 + j], gg = gm[1024 + j], go = gm[1536 + j];
  const float cv = fsig(gf) * c[idx] + fsig(gi) * ftanhf(gg);
  const float h = fsig(go) * ftanhf(cv);
  c[idx] = cv;
  cbuf2[(size_t)b * 1024 + j] = (f16)h;
  if (t + 1 < Tt) cbuf1[((size_t)(t + 1) * 1024 + b) * 768 + 256 + j] = (f16)h;
}

__global__ __launch_bounds__(256)
void cell2_k(const float* __restrict__ g, float* __restrict__ c,
             f16* __restrict__ cbuf2, f16* __restrict__ hall, int t) {
  const int idx = blockIdx.x * 256 + threadIdx.x;
  const int b = idx >> 9, j = idx & 511;
  const float* gm = g + (size_t)b * 2048;
  const float gi = gm[j], gf = gm[512 + j], gg = gm[1024 + j], go = gm[1536 + j];
  const float cv = fsig(gf) * c[idx] + fsig(gi) * ftanhf(gg);
  const float h = fsig(go) * ftanhf(cv);
  c[idx] = cv;
  cbuf2[(size_t)b * 1024 + 512 + j] = (f16)h;
  hall[((size_t)t * 1024 + b) * 512 + j] = (f16)h;
}

__global__ __launch_bounds__(256)
void post_all_k(const f16* __restrict__ mv, const float* __restrict__ z,
                double* __restrict__ acc) {
  const int n = BT * Zd;
  double local = 0.0;
  for (int i = blockIdx.x * blockDim.x + threadIdx.x; i < n; i += gridDim.x * blockDim.x) {
    const int k = i & 255;
    const int row = i >> 8;
    const int t = row >> 10, b = row & 1023;
    const float mean = (float)mv[(size_t)row * 512 + k];
    const float lv = (float)mv[(size_t)row * 512 + 256 + k];
    const float zv = z[((size_t)b * 16 + t) * 256 + k];
    const float d = (zv - mean) * __expf(-lv);
    local += (double)(-0.5f * d * d - LOG_SQRT_2PI_F) - (double)lv;
  }
  local = block_reduce_d(local);
  if (threadIdx.x == 0) atomicAdd(acc + 0, local);
}

__global__ void finalize_k(const double* __restrict__ acc, float* __restrict__ out) {
  const double loglik = 0.0025 * acc[0] + acc[1];
  out[0] = (float)(-loglik / (double)Bb);
}

// ---------------- weight conversion ----------------
__global__ __launch_bounds__(256)
void cvt_k(const float* __restrict__ s, f16* __restrict__ d, int n) {
  for (int i = blockIdx.x * blockDim.x + threadIdx.x; i < n; i += gridDim.x * blockDim.x)
    d[i] = (f16)s[i];
}

__global__ __launch_bounds__(256)
void cvt_cat_rows_k(const float* __restrict__ a, const float* __restrict__ b,
                    f16* __restrict__ d, int L, int R, int K) {
  const int n = L * 2 * R * K;
  for (int i = blockIdx.x * blockDim.x + threadIdx.x; i < n; i += gridDim.x * blockDim.x) {
    const int k = i % K;
    const int rem = i / K;
    const int r = rem % (2 * R);
    const int l = rem / (2 * R);
    const float v = (r < R) ? a[((size_t)l * R + r) * K + k]
                            : b[((size_t)l * R + (r - R)) * K + k];
    d[i] = (f16)v;
  }
}

__global__ __launch_bounds__(256)
void cvt_cat_cols_k(const float* __restrict__ a, int KA, const float* __restrict__ b,
                    int KB, f16* __restrict__ d, int R) {
  const int n = R * (KA + KB);
  for (int i = blockIdx.x * blockDim.x + threadIdx.x; i < n; i += gridDim.x * blockDim.x) {
    const int c = i % (KA + KB);
    const int r = i / (KA + KB);
    const float v = (c < KA) ? a[(size_t)r * KA + c] : b[(size_t)r * KB + (c - KA)];
    d[i] = (f16)v;
  }
}

__global__ __launch_bounds__(256)
void fcat_k(const float* __restrict__ a, const float* __restrict__ b,
            float* __restrict__ d, int L, int R) {
  const int n = L * 2 * R;
  for (int i = blockIdx.x * blockDim.x + threadIdx.x; i < n; i += gridDim.x * blockDim.x) {
    const int c = i % (2 * R);
    const int l = i / (2 * R);
    d[i] = (c < R) ? a[(size_t)l * R + c] : b[(size_t)l * R + (c - R)];
  }
}

// ---------------- host launch ----------------
extern "C" void kernel_launch(void* const* d_in, const int* in_sizes, int n_in,
                              void* d_out, int out_size, void* d_ws, size_t ws_size,
                              hipStream_t stream) {
  (void)in_sizes; (void)n_in; (void)out_size; (void)ws_size;

  const float* nf    = (const float*)d_in[0];
  const float* sW1   = (const float*)d_in[1];
  const float* sb1   = (const float*)d_in[2];
  const float* sW2   = (const float*)d_in[3];
  const float* sb2   = (const float*)d_in[4];
  const float* sW3   = (const float*)d_in[5];
  const float* sb3   = (const float*)d_in[6];
  const float* tW1   = (const float*)d_in[7];
  const float* tb1   = (const float*)d_in[8];
  const float* tW2   = (const float*)d_in[9];
  const float* tb2   = (const float*)d_in[10];
  const float* tW3   = (const float*)d_in[11];
  const float* tb3   = (const float*)d_in[12];
  const float* l1Wih = (const float*)d_in[13];
  const float* l1Whh = (const float*)d_in[14];
  const float* l1bih = (const float*)d_in[15];
  const float* l1bhh = (const float*)d_in[16];
  const float* l2Wih = (const float*)d_in[17];
  const float* l2Whh = (const float*)d_in[18];
  const float* l2bih = (const float*)d_in[19];
  const float* l2bhh = (const float*)d_in[20];
  const float* mW    = (const float*)d_in[21];
  const float* mb    = (const float*)d_in[22];
  const float* lvW   = (const float*)d_in[23];
  const float* lvb   = (const float*)d_in[24];

  float* out = (float*)d_out;

  char* wsb = (char*)d_ws;
  size_t off = 0;
  auto alloc = [&](size_t bytes) -> char* {
    char* p = wsb + off;
    off += (bytes + 255) & ~(size_t)255;
    return p;
  };
  double* acc  = (double*)alloc(16);
  float*  z    = (float*)alloc((size_t)BT * Zd * 4);
  f16*    inp  = (f16*)alloc((size_t)BT * 512 * 2);   // LSTM: mvbuf
  f16*    hidA = (f16*)alloc((size_t)BT * 1024 * 2);  // LSTM: cbuf1+cbuf2
  f16*    hidB = (f16*)alloc((size_t)BT * 1024 * 2);  // LSTM: hall+gates
  f16*    s16  = (f16*)alloc((size_t)BT * Zd * 2);    // LSTM: c1,c2
  f16*    t16  = (f16*)alloc((size_t)BT * Zd * 2);
  float*  ldj  = (float*)alloc((size_t)BT * 4);
  f16* w1cat = (f16*)alloc((size_t)9 * 1024 * 512 * 2);
  f16* w2s   = (f16*)alloc((size_t)9 * 512 * 512 * 2);
  f16* w2t   = (f16*)alloc((size_t)9 * 512 * 512 * 2);
  f16* w3s   = (f16*)alloc((size_t)9 * 256 * 512 * 2);
  f16* w3t   = (f16*)alloc((size_t)9 * 256 * 512 * 2);
  f16* wcat1 = (f16*)alloc((size_t)2048 * 768 * 2);
  f16* wcat2 = (f16*)alloc((size_t)2048 * 1024 * 2);
  f16* wmv   = (f16*)alloc((size_t)512 * 512 * 2);
  float* bcat1 = (float*)alloc((size_t)9 * 1024 * 4);
  float* bmv   = (float*)alloc((size_t)512 * 4);

  f16*   cbuf1 = hidA;                               // [16][1024][768]
  f16*   cbuf2 = hidA + (size_t)16 * 1024 * 768;     // [1024][1024]
  f16*   hall  = hidB;                               // [16384][512]
  float* gates = (float*)(hidB + (size_t)BT * 512);  // [1024][2048] fp32
  float* c1    = (float*)s16;                        // [1024][512] fp32
  float* c2    = (float*)s16 + (size_t)Bb * Hh;
  f16*   mvbuf = inp;                                // [16384][512]

  // ---- weight conversions ----
  cvt_cat_rows_k<<<2048, 256, 0, stream>>>(sW1, tW1, w1cat, 9, 512, 512);
  cvt_k<<<2048, 256, 0, stream>>>(sW2, w2s, 9 * 512 * 512);
  cvt_k<<<2048, 256, 0, stream>>>(tW2, w2t, 9 * 512 * 512);
  cvt_k<<<1024, 256, 0, stream>>>(sW3, w3s, 9 * 256 * 512);
  cvt_k<<<1024, 256, 0, stream>>>(tW3, w3t, 9 * 256 * 512);
  cvt_cat_cols_k<<<1024, 256, 0, stream>>>(l1Wih, 256, l1Whh, 512, wcat1, 2048);
  cvt_cat_cols_k<<<1024, 256, 0, stream>>>(l2Wih, 512, l2Whh, 512, wcat2, 2048);
  cvt_cat_rows_k<<<256, 256, 0, stream>>>(mW, lvW, wmv, 1, 256, 512);
  fcat_k<<<16, 256, 0, stream>>>(sb1, tb1, bcat1, 9, 512);
  fcat_k<<<2, 256, 0, stream>>>(mb, lvb, bmv, 1, 256);

  hipMemsetAsync(acc, 0, 16, stream);
  hipMemsetAsync(ldj, 0, (size_t)BT * 4, stream);

  split_k<<<2048, 256, 0, stream>>>(nf, z, inp);

  // ---- inverse flow: layers 8..0 ----
  for (int i = NL - 1; i >= 0; --i) {
    hgemm2_k<EPI_LEAKY, EPI_LEAKY><<<dim3(128, 8, 1), 256, 0, stream>>>(
        inp, inp, 512, w1cat + (size_t)i * 1024 * 512, w1cat + (size_t)i * 1024 * 512,
        512, bcat1 + i * 1024, bcat1 + i * 1024, hidA, hidA, 1024, 0);
    hgemm2_k<EPI_LEAKY, EPI_LEAKY><<<dim3(128, 4, 2), 256, 0, stream>>>(
        hidA, hidA + 512, 1024, w2s + (size_t)i * 512 * 512, w2t + (size_t)i * 512 * 512,
        512, sb2 + i * 512, tb2 + i * 512, hidB, hidB + 512, 1024, 0);
    hgemm2_k<EPI_S, EPI_T><<<dim3(128, 2, 2), 256, 0, stream>>>(
        hidB, hidB + 512, 1024, w3s + (size_t)i * 256 * 512, w3t + (size_t)i * 256 * 512,
        512, sb3 + i * 256, tb3 + i * 256, s16, t16, 256, i);
    flow_update_k<<<BT / 4, 256, 0, stream>>>(z, s16, t16, ldj, inp, i, i - 1);
    if (i - 1 == 0) prep0_k<<<2048, 256, 0, stream>>>(z, inp);
  }

  z3_out_k<<<1024, 256, 0, stream>>>(z, out, acc);
  ldj_sum_k<<<64, 256, 0, stream>>>(ldj, acc);

  // ---- LSTM prior ----
  hipMemsetAsync(cbuf1, 0, (size_t)1024 * 768 * 2, stream);
  hipMemsetAsync(cbuf2, 0, (size_t)1024 * 1024 * 2, stream);
  hipMemsetAsync(c1, 0, (size_t)Bb * Hh * 4 * 2, stream);
  xfill_k<<<2048, 256, 0, stream>>>(z, cbuf1);

  for (int t = 0; t < Tt; ++t) {
    hgemm64_k<<<dim3(16, 32), 256, 0, stream>>>(
        cbuf1 + (size_t)t * 1024 * 768, 768, wcat1, 768, l1bih, l1bhh, gates, 2048);
    cell1_k<<<2048, 256, 0, stream>>>(gates, c1, cbuf2, cbuf1, t);
    hgemm64_k<<<dim3(16, 32), 256, 0, stream>>>(
        cbuf2, 1024, wcat2, 1024, l2bih, l2bhh, gates, 2048);
    cell2_k<<<2048, 256, 0, stream>>>(gates, c2, cbuf2, hall, t);
  }

  hgemm2_k<EPI_MV, EPI_MV><<<dim3(128, 4, 1), 256, 0, stream>>>(
      hall, hall, 512, wmv, wmv, 512, bmv, bmv, mvbuf, mvbuf, 512, 0);
  post_all_k<<<1024, 256, 0, stream>>>(mvbuf, z, acc);

  finalize_k<<<1, 1, 0, stream>>>(acc, out);
}